// Round 1
// baseline (5476.839 us; speedup 1.0000x reference)
//
#include <hip/hip_runtime.h>
#include <math.h>

#define B_ROWS 2048
#define D_K    2048
#define N_CLS  50257
#define GN     393                 // ceil(50257/128)
#define N_PAD  (GN * 128)          // 50304
#define GM     16                  // 2048/128
#define KSTEPS (D_K / 64)          // 32

typedef __attribute__((ext_vector_type(8))) short          bf16x8;
typedef __attribute__((ext_vector_type(4))) float          f32x4;
typedef __attribute__((ext_vector_type(8))) unsigned short u16x8;

typedef __attribute__((address_space(1))) const void as1cv;
typedef __attribute__((address_space(3))) void       as3v;

__device__ __forceinline__ void glds16(const void* g, void* l) {
  __builtin_amdgcn_global_load_lds((as1cv*)g, (as3v*)l, 16, 0, 0);
}

__device__ __forceinline__ unsigned short f2bf(float x) {
  unsigned int u = __builtin_bit_cast(unsigned int, x);
  u += 0x7fffu + ((u >> 16) & 1u);   // round-to-nearest-even
  return (unsigned short)(u >> 16);
}

// ---------- fp32 -> bf16 conversion (W zero-padded to N_PAD rows) ----------
__global__ void conv_w(const float* __restrict__ W, unsigned short* __restrict__ Wb) {
  const size_t NU = (size_t)N_PAD * D_K / 8;
  const size_t stride = (size_t)gridDim.x * blockDim.x;
  for (size_t u = (size_t)blockIdx.x * blockDim.x + threadIdx.x; u < NU; u += stride) {
    const size_t e = u * 8;
    u16x8 o = {0, 0, 0, 0, 0, 0, 0, 0};
    if ((e >> 11) < (size_t)N_CLS) {
      const float4 a = *(const float4*)(W + e);
      const float4 b = *(const float4*)(W + e + 4);
      o[0] = f2bf(a.x); o[1] = f2bf(a.y); o[2] = f2bf(a.z); o[3] = f2bf(a.w);
      o[4] = f2bf(b.x); o[5] = f2bf(b.y); o[6] = f2bf(b.z); o[7] = f2bf(b.w);
    }
    *(u16x8*)(Wb + e) = o;
  }
}

__global__ void conv_e(const float* __restrict__ E, unsigned short* __restrict__ Eb) {
  const size_t NU = (size_t)B_ROWS * D_K / 8;
  const size_t stride = (size_t)gridDim.x * blockDim.x;
  for (size_t u = (size_t)blockIdx.x * blockDim.x + threadIdx.x; u < NU; u += stride) {
    const size_t e = u * 8;
    const float4 a = *(const float4*)(E + e);
    const float4 b = *(const float4*)(E + e + 4);
    u16x8 o;
    o[0] = f2bf(a.x); o[1] = f2bf(a.y); o[2] = f2bf(a.z); o[3] = f2bf(a.w);
    o[4] = f2bf(b.x); o[5] = f2bf(b.y); o[6] = f2bf(b.z); o[7] = f2bf(b.w);
    *(u16x8*)(Eb + e) = o;
  }
}

// ---------- fused GEMM + per-tile row stats ----------
// logits[m][n] = sum_k E[m][k] * W[n][k]; tile 128x128, BK=64, 4 waves (2x2).
__global__ __launch_bounds__(256) void gemm_ce(
    const unsigned short* __restrict__ Eb,
    const unsigned short* __restrict__ Wb,
    const int* __restrict__ labels,
    float* __restrict__ pm, float* __restrict__ ps, float* __restrict__ pt,
    float* __restrict__ ly)
{
  __shared__ unsigned short As[128 * 64];
  __shared__ unsigned short Ws[128 * 64];
  __shared__ float s_m[128][2], s_s[128][2], s_t[128][2];

  const int tid  = threadIdx.x;
  const int wid  = tid >> 6;
  const int lane = tid & 63;
  const int wm   = wid >> 1;
  const int wn   = wid & 1;
  const int l16  = lane & 15;
  const int lhi  = lane >> 4;

  const int n_tile = blockIdx.x / GM;   // 16 consecutive blocks share a W panel
  const int m_tile = blockIdx.x % GM;

  f32x4 acc[4][4] = {};

  const int srow_in_chunk = lane >> 3;   // 0..7
  const int scol = (lane & 7) * 8;       // 0..56

  const unsigned short* Ag = Eb + (size_t)(m_tile * 128) * D_K;
  const unsigned short* Wg = Wb + (size_t)(n_tile * 128) * D_K;

  for (int kt = 0; kt < KSTEPS; ++kt) {
    const int k0 = kt * 64;
#pragma unroll
    for (int q = 0; q < 4; ++q) {
      const int chunk = wid * 4 + q;               // 0..15 (wave-uniform)
      const int row = chunk * 8 + srow_in_chunk;   // 0..127
      glds16(Ag + (size_t)row * D_K + k0 + scol, (char*)As + chunk * 1024);
      glds16(Wg + (size_t)row * D_K + k0 + scol, (char*)Ws + chunk * 1024);
    }
    __syncthreads();
#pragma unroll
    for (int kk = 0; kk < 2; ++kk) {
      bf16x8 af[4], wf[4];
#pragma unroll
      for (int i = 0; i < 4; ++i)
        af[i] = *(const bf16x8*)&As[(wm * 64 + i * 16 + l16) * 64 + kk * 32 + lhi * 8];
#pragma unroll
      for (int j = 0; j < 4; ++j)
        wf[j] = *(const bf16x8*)&Ws[(wn * 64 + j * 16 + l16) * 64 + kk * 32 + lhi * 8];
#pragma unroll
      for (int i = 0; i < 4; ++i)
#pragma unroll
        for (int j = 0; j < 4; ++j)
          acc[i][j] = __builtin_amdgcn_mfma_f32_16x16x32_bf16(af[i], wf[j], acc[i][j], 0, 0, 0);
    }
    __syncthreads();
  }

  // Epilogue: per-row (max, sumexp, sum) over this tile's 128 cols + label gather.
  // C/D layout: col = lane&15, row = (lane>>4)*4 + reg  [verified m89/m91]
  const int row_base = m_tile * 128;
  const int col_base = n_tile * 128 + wn * 64;

#pragma unroll
  for (int i = 0; i < 4; ++i) {
#pragma unroll
    for (int r = 0; r < 4; ++r) {
      const int rt  = wm * 64 + i * 16 + lhi * 4 + r;
      const int row = row_base + rt;
      const int lab = labels[row];
      const int rel = lab - col_base - l16;
      if (rel >= 0 && rel < 64 && (rel & 15) == 0)
        ly[row] = acc[i][rel >> 4][r];

      float mx = -INFINITY, sm = 0.f;
#pragma unroll
      for (int j = 0; j < 4; ++j) {
        const bool v = (col_base + j * 16 + l16) < N_CLS;
        const float x = acc[i][j][r];
        if (v) { mx = fmaxf(mx, x); sm += x; }
      }
#pragma unroll
      for (int d = 1; d < 16; d <<= 1) {
        mx = fmaxf(mx, __shfl_xor(mx, d));
        sm += __shfl_xor(sm, d);
      }
      float se = 0.f;
#pragma unroll
      for (int j = 0; j < 4; ++j) {
        const bool v = (col_base + j * 16 + l16) < N_CLS;
        if (v) se += __expf(acc[i][j][r] - mx);
      }
#pragma unroll
      for (int d = 1; d < 16; d <<= 1) se += __shfl_xor(se, d);

      if (l16 == 0) { s_m[rt][wn] = mx; s_s[rt][wn] = se; s_t[rt][wn] = sm; }
    }
  }
  __syncthreads();
  if (tid < 128) {
    const float m0 = s_m[tid][0], m1 = s_m[tid][1];
    const float M = fmaxf(m0, m1);
    const float S = s_s[tid][0] * __expf(m0 - M) + s_s[tid][1] * __expf(m1 - M);
    const float T = s_t[tid][0] + s_t[tid][1];
    const size_t o = (size_t)n_tile * B_ROWS + row_base + tid;
    pm[o] = M; ps[o] = S; pt[o] = T;
  }
}

// ---------- final combine: 393 partials per row -> loss ----------
__global__ void ce_reduce(const float* __restrict__ pm, const float* __restrict__ ps,
                          const float* __restrict__ pt, const float* __restrict__ ly,
                          float* __restrict__ out)
{
  const int tid = threadIdx.x;
  const int row = blockIdx.x * blockDim.x + tid;
  float M = -INFINITY, S = 0.f, T = 0.f;
  for (int nt = 0; nt < GN; ++nt) {
    const size_t o = (size_t)nt * B_ROWS + row;
    const float m = pm[o], s = ps[o], t = pt[o];
    const float Mn = fmaxf(M, m);
    S = S * __expf(M - Mn) + s * __expf(m - Mn);
    M = Mn;
    T += t;
  }
  const float lse = M + logf(S);
  float per = lse - 0.9f * ly[row] - 0.1f * (T * (1.0f / (float)N_CLS));
#pragma unroll
  for (int d = 1; d < 64; d <<= 1) per += __shfl_xor(per, d);
  __shared__ float red[4];
  if ((tid & 63) == 0) red[tid >> 6] = per;
  __syncthreads();
  if (tid == 0)
    atomicAdd(out, (red[0] + red[1] + red[2] + red[3]) * (1.0f / B_ROWS));
}

extern "C" void kernel_launch(void* const* d_in, const int* in_sizes, int n_in,
                              void* d_out, int out_size, void* d_ws, size_t ws_size,
                              hipStream_t stream)
{
  const float* E      = (const float*)d_in[0];
  const int*   labels = (const int*)  d_in[1];
  const float* W      = (const float*)d_in[2];
  float* out = (float*)d_out;

  char* ws = (char*)d_ws;
  unsigned short* Wb = (unsigned short*)ws;
  size_t off = (size_t)N_PAD * D_K * 2;            // 206,045,184 B
  unsigned short* Eb = (unsigned short*)(ws + off);
  off += (size_t)B_ROWS * D_K * 2;                 // + 8,388,608 B
  float* pm = (float*)(ws + off); off += (size_t)GN * B_ROWS * 4;
  float* ps = (float*)(ws + off); off += (size_t)GN * B_ROWS * 4;
  float* pt = (float*)(ws + off); off += (size_t)GN * B_ROWS * 4;
  float* ly = (float*)(ws + off);                  // total ~224 MB

  hipMemsetAsync(d_out, 0, sizeof(float), stream);
  conv_w<<<dim3(2048), dim3(256), 0, stream>>>(W, Wb);
  conv_e<<<dim3(512),  dim3(256), 0, stream>>>(E, Eb);
  gemm_ce<<<dim3(GM * GN), dim3(256), 0, stream>>>(Eb, Wb, labels, pm, ps, pt, ly);
  ce_reduce<<<dim3(B_ROWS / 256), dim3(256), 0, stream>>>(pm, ps, pt, ly, out);
}

// Round 2
// 926.607 us; speedup vs baseline: 5.9106x; 5.9106x over previous
//
#include <hip/hip_runtime.h>
#include <math.h>

#define B_ROWS 2048
#define D_K    2048
#define N_CLS  50257
#define GN     393                 // ceil(50257/128)
#define N_PAD  (GN * 128)          // 50304
#define GM     16                  // 2048/128
#define KSTEPS (D_K / 64)          // 32

typedef __attribute__((ext_vector_type(8))) short          bf16x8;
typedef __attribute__((ext_vector_type(4))) float          f32x4;
typedef __attribute__((ext_vector_type(8))) unsigned short u16x8;

typedef __attribute__((address_space(1))) const void as1cv;
typedef __attribute__((address_space(3))) void       as3v;

__device__ __forceinline__ void glds16(const void* g, void* l) {
  __builtin_amdgcn_global_load_lds((as1cv*)g, (as3v*)l, 16, 0, 0);
}

__device__ __forceinline__ unsigned short f2bf(float x) {
  unsigned int u = __builtin_bit_cast(unsigned int, x);
  u += 0x7fffu + ((u >> 16) & 1u);   // round-to-nearest-even
  return (unsigned short)(u >> 16);
}

// ---------- fp32 -> bf16 conversion (W zero-padded to N_PAD rows) ----------
__global__ void conv_w(const float* __restrict__ W, unsigned short* __restrict__ Wb) {
  const size_t NU = (size_t)N_PAD * D_K / 8;
  const size_t stride = (size_t)gridDim.x * blockDim.x;
  for (size_t u = (size_t)blockIdx.x * blockDim.x + threadIdx.x; u < NU; u += stride) {
    const size_t e = u * 8;
    u16x8 o = {0, 0, 0, 0, 0, 0, 0, 0};
    if ((e >> 11) < (size_t)N_CLS) {
      const float4 a = *(const float4*)(W + e);
      const float4 b = *(const float4*)(W + e + 4);
      o[0] = f2bf(a.x); o[1] = f2bf(a.y); o[2] = f2bf(a.z); o[3] = f2bf(a.w);
      o[4] = f2bf(b.x); o[5] = f2bf(b.y); o[6] = f2bf(b.z); o[7] = f2bf(b.w);
    }
    *(u16x8*)(Wb + e) = o;
  }
}

__global__ void conv_e(const float* __restrict__ E, unsigned short* __restrict__ Eb) {
  const size_t NU = (size_t)B_ROWS * D_K / 8;
  const size_t stride = (size_t)gridDim.x * blockDim.x;
  for (size_t u = (size_t)blockIdx.x * blockDim.x + threadIdx.x; u < NU; u += stride) {
    const size_t e = u * 8;
    const float4 a = *(const float4*)(E + e);
    const float4 b = *(const float4*)(E + e + 4);
    u16x8 o;
    o[0] = f2bf(a.x); o[1] = f2bf(a.y); o[2] = f2bf(a.z); o[3] = f2bf(a.w);
    o[4] = f2bf(b.x); o[5] = f2bf(b.y); o[6] = f2bf(b.z); o[7] = f2bf(b.w);
    *(u16x8*)(Eb + e) = o;
  }
}

// ---------- fused GEMM + per-tile row stats ----------
// logits[m][n] = sum_k E[m][k] * W[n][k]; tile 128x128, BK=64, 4 waves (2x2).
__global__ __launch_bounds__(256) void gemm_ce(
    const unsigned short* __restrict__ Eb,
    const unsigned short* __restrict__ Wb,
    const int* __restrict__ labels,
    float* __restrict__ pm, float* __restrict__ ps, float* __restrict__ pt,
    float* __restrict__ ly)
{
  __shared__ unsigned short As[128 * 64];
  __shared__ unsigned short Ws[128 * 64];
  __shared__ float s_m[128][2], s_s[128][2], s_t[128][2];

  const int tid  = threadIdx.x;
  const int wid  = tid >> 6;
  const int lane = tid & 63;
  const int wm   = wid >> 1;
  const int wn   = wid & 1;
  const int l16  = lane & 15;
  const int lhi  = lane >> 4;

  const int n_tile = blockIdx.x / GM;   // 16 consecutive blocks share a W panel
  const int m_tile = blockIdx.x % GM;

  f32x4 acc[4][4] = {};

  const int srow_in_chunk = lane >> 3;   // 0..7
  const int scol = (lane & 7) * 8;       // 0..56

  const unsigned short* Ag = Eb + (size_t)(m_tile * 128) * D_K;
  const unsigned short* Wg = Wb + (size_t)(n_tile * 128) * D_K;

  for (int kt = 0; kt < KSTEPS; ++kt) {
    const int k0 = kt * 64;
#pragma unroll
    for (int q = 0; q < 4; ++q) {
      const int chunk = wid * 4 + q;               // 0..15 (wave-uniform)
      const int row = chunk * 8 + srow_in_chunk;   // 0..127
      glds16(Ag + (size_t)row * D_K + k0 + scol, (char*)As + chunk * 1024);
      glds16(Wg + (size_t)row * D_K + k0 + scol, (char*)Ws + chunk * 1024);
    }
    __syncthreads();
#pragma unroll
    for (int kk = 0; kk < 2; ++kk) {
      bf16x8 af[4], wf[4];
#pragma unroll
      for (int i = 0; i < 4; ++i)
        af[i] = *(const bf16x8*)&As[(wm * 64 + i * 16 + l16) * 64 + kk * 32 + lhi * 8];
#pragma unroll
      for (int j = 0; j < 4; ++j)
        wf[j] = *(const bf16x8*)&Ws[(wn * 64 + j * 16 + l16) * 64 + kk * 32 + lhi * 8];
#pragma unroll
      for (int i = 0; i < 4; ++i)
#pragma unroll
        for (int j = 0; j < 4; ++j)
          acc[i][j] = __builtin_amdgcn_mfma_f32_16x16x32_bf16(af[i], wf[j], acc[i][j], 0, 0, 0);
    }
    __syncthreads();
  }

  // Epilogue: per-row (max, sumexp, sum) over this tile's 128 cols + label gather.
  // C/D layout: col = lane&15, row = (lane>>4)*4 + reg  [verified m89/m91]
  const int row_base = m_tile * 128;
  const int col_base = n_tile * 128 + wn * 64;

#pragma unroll
  for (int i = 0; i < 4; ++i) {
#pragma unroll
    for (int r = 0; r < 4; ++r) {
      const int rt  = wm * 64 + i * 16 + lhi * 4 + r;
      const int row = row_base + rt;
      const int lab = labels[row];
      const int rel = lab - col_base - l16;
      // Compile-time acc indices only (rule #20: no runtime index into acc).
#pragma unroll
      for (int j = 0; j < 4; ++j) {
        if (rel == j * 16) ly[row] = acc[i][j][r];
      }

      float mx = -INFINITY, sm = 0.f;
#pragma unroll
      for (int j = 0; j < 4; ++j) {
        const bool v = (col_base + j * 16 + l16) < N_CLS;
        const float x = acc[i][j][r];
        if (v) { mx = fmaxf(mx, x); sm += x; }
      }
#pragma unroll
      for (int d = 1; d < 16; d <<= 1) {
        mx = fmaxf(mx, __shfl_xor(mx, d));
        sm += __shfl_xor(sm, d);
      }
      float se = 0.f;
#pragma unroll
      for (int j = 0; j < 4; ++j) {
        const bool v = (col_base + j * 16 + l16) < N_CLS;
        if (v) se += __expf(acc[i][j][r] - mx);
      }
#pragma unroll
      for (int d = 1; d < 16; d <<= 1) se += __shfl_xor(se, d);

      if (l16 == 0) { s_m[rt][wn] = mx; s_s[rt][wn] = se; s_t[rt][wn] = sm; }
    }
  }
  __syncthreads();
  if (tid < 128) {
    const float m0 = s_m[tid][0], m1 = s_m[tid][1];
    const float M = fmaxf(m0, m1);
    const float S = s_s[tid][0] * __expf(m0 - M) + s_s[tid][1] * __expf(m1 - M);
    const float T = s_t[tid][0] + s_t[tid][1];
    const size_t o = (size_t)n_tile * B_ROWS + row_base + tid;
    pm[o] = M; ps[o] = S; pt[o] = T;
  }
}

// ---------- final combine: 393 partials per row -> loss ----------
__global__ void ce_reduce(const float* __restrict__ pm, const float* __restrict__ ps,
                          const float* __restrict__ pt, const float* __restrict__ ly,
                          float* __restrict__ out)
{
  const int tid = threadIdx.x;
  const int row = blockIdx.x * blockDim.x + tid;
  float M = -INFINITY, S = 0.f, T = 0.f;
  for (int nt = 0; nt < GN; ++nt) {
    const size_t o = (size_t)nt * B_ROWS + row;
    const float m = pm[o], s = ps[o], t = pt[o];
    const float Mn = fmaxf(M, m);
    S = S * __expf(M - Mn) + s * __expf(m - Mn);
    M = Mn;
    T += t;
  }
  const float lse = M + logf(S);
  float per = lse - 0.9f * ly[row] - 0.1f * (T * (1.0f / (float)N_CLS));
#pragma unroll
  for (int d = 1; d < 64; d <<= 1) per += __shfl_xor(per, d);
  __shared__ float red[4];
  if ((tid & 63) == 0) red[tid >> 6] = per;
  __syncthreads();
  if (tid == 0)
    atomicAdd(out, (red[0] + red[1] + red[2] + red[3]) * (1.0f / B_ROWS));
}

extern "C" void kernel_launch(void* const* d_in, const int* in_sizes, int n_in,
                              void* d_out, int out_size, void* d_ws, size_t ws_size,
                              hipStream_t stream)
{
  const float* E      = (const float*)d_in[0];
  const int*   labels = (const int*)  d_in[1];
  const float* W      = (const float*)d_in[2];
  float* out = (float*)d_out;

  char* ws = (char*)d_ws;
  unsigned short* Wb = (unsigned short*)ws;
  size_t off = (size_t)N_PAD * D_K * 2;            // 206,045,184 B
  unsigned short* Eb = (unsigned short*)(ws + off);
  off += (size_t)B_ROWS * D_K * 2;                 // + 8,388,608 B
  float* pm = (float*)(ws + off); off += (size_t)GN * B_ROWS * 4;
  float* ps = (float*)(ws + off); off += (size_t)GN * B_ROWS * 4;
  float* pt = (float*)(ws + off); off += (size_t)GN * B_ROWS * 4;
  float* ly = (float*)(ws + off);                  // total ~224 MB

  hipMemsetAsync(d_out, 0, sizeof(float), stream);
  conv_w<<<dim3(2048), dim3(256), 0, stream>>>(W, Wb);
  conv_e<<<dim3(512),  dim3(256), 0, stream>>>(E, Eb);
  gemm_ce<<<dim3(GM * GN), dim3(256), 0, stream>>>(Eb, Wb, labels, pm, ps, pt, ly);
  ce_reduce<<<dim3(B_ROWS / 256), dim3(256), 0, stream>>>(pm, ps, pt, ly, out);
}

// Round 3
// 698.372 us; speedup vs baseline: 7.8423x; 1.3268x over previous
//
#include <hip/hip_runtime.h>
#include <math.h>

#define B_ROWS 2048
#define D_K    2048
#define N_CLS  50257
#define BM     128
#define BN     256
#define BK     64
#define NT     (D_K / BK)       // 32 K-tiles
#define GM     16               // 2048/128 m-tiles
#define GN     197              // ceil(50257/256) n-tiles
#define N_PAD  (GN * BN)        // 50432
#define NWG    (GM * GN)        // 3152 = 8*394 (bijective XCD swizzle)

#define ABYTES 16384            // 128x64 bf16
#define BBYTES 32768            // 256x64 bf16
#define BUFB   (ABYTES + BBYTES)// 49152 per buffer
#define STATS  (3 * BUFB)       // 147456: stats region offset

typedef __attribute__((ext_vector_type(8))) short          bf16x8;
typedef __attribute__((ext_vector_type(4))) float          f32x4;
typedef __attribute__((ext_vector_type(8))) unsigned short u16x8;

typedef __attribute__((address_space(1))) const void as1cv;
typedef __attribute__((address_space(3))) void       as3v;

__device__ __forceinline__ void glds16(const void* g, void* l) {
  __builtin_amdgcn_global_load_lds((as1cv*)g, (as3v*)l, 16, 0, 0);
}
__device__ __forceinline__ void bar() {
  __builtin_amdgcn_sched_barrier(0);
  __builtin_amdgcn_s_barrier();
  __builtin_amdgcn_sched_barrier(0);
}

__device__ __forceinline__ unsigned short f2bf(float x) {
  unsigned int u = __builtin_bit_cast(unsigned int, x);
  u += 0x7fffu + ((u >> 16) & 1u);   // RNE
  return (unsigned short)(u >> 16);
}

// ---------- fp32 -> bf16 (W zero-padded to N_PAD rows) ----------
__global__ void conv_w(const float* __restrict__ W, unsigned short* __restrict__ Wb) {
  const size_t NU = (size_t)N_PAD * D_K / 8;
  const size_t stride = (size_t)gridDim.x * blockDim.x;
  for (size_t u = (size_t)blockIdx.x * blockDim.x + threadIdx.x; u < NU; u += stride) {
    const size_t e = u * 8;
    u16x8 o = {0, 0, 0, 0, 0, 0, 0, 0};
    if ((e >> 11) < (size_t)N_CLS) {
      const float4 a = *(const float4*)(W + e);
      const float4 b = *(const float4*)(W + e + 4);
      o[0] = f2bf(a.x); o[1] = f2bf(a.y); o[2] = f2bf(a.z); o[3] = f2bf(a.w);
      o[4] = f2bf(b.x); o[5] = f2bf(b.y); o[6] = f2bf(b.z); o[7] = f2bf(b.w);
    }
    *(u16x8*)(Wb + e) = o;
  }
}

__global__ void conv_e(const float* __restrict__ E, unsigned short* __restrict__ Eb) {
  const size_t NU = (size_t)B_ROWS * D_K / 8;
  const size_t stride = (size_t)gridDim.x * blockDim.x;
  for (size_t u = (size_t)blockIdx.x * blockDim.x + threadIdx.x; u < NU; u += stride) {
    const size_t e = u * 8;
    const float4 a = *(const float4*)(E + e);
    const float4 b = *(const float4*)(E + e + 4);
    u16x8 o;
    o[0] = f2bf(a.x); o[1] = f2bf(a.y); o[2] = f2bf(a.z); o[3] = f2bf(a.w);
    o[4] = f2bf(b.x); o[5] = f2bf(b.y); o[6] = f2bf(b.z); o[7] = f2bf(b.w);
    *(u16x8*)(Eb + e) = o;
  }
}

// ---------- fused GEMM + per-tile row stats: 8-phase-style schedule ----------
// 3-buffer LDS rotation, prefetch distance 2, counted vmcnt(6), T2 XOR swizzle,
// T5 setprio. 8 waves = 2M x 4N, per-wave 64x64, acc[4][4].
__global__ __launch_bounds__(512, 2) void gemm_ce(
    const unsigned short* __restrict__ Eb,
    const unsigned short* __restrict__ Wb,
    const int* __restrict__ labels,
    float* __restrict__ pm, float* __restrict__ ps, float* __restrict__ pt,
    float* __restrict__ ly)
{
  __shared__ __align__(16) char lds[STATS + 6144];
  float (*s_m)[4] = (float (*)[4])(lds + STATS);
  float (*s_s)[4] = (float (*)[4])(lds + STATS + 2048);
  float (*s_t)[4] = (float (*)[4])(lds + STATS + 4096);

  const int tid  = threadIdx.x;
  const int wid  = tid >> 6;
  const int lane = tid & 63;
  const int wm   = wid >> 2;       // 0..1
  const int wn   = wid & 3;        // 0..3
  const int l16  = lane & 15;
  const int lhi  = lane >> 4;
  const int sw   = lane & 7;

  // XCD-aware bijective swizzle
  const int bid     = blockIdx.x;
  const int logical = (bid & 7) * (NWG / 8) + (bid >> 3);
  const int n_tile  = logical / GM;
  const int m_tile  = logical % GM;

  // ---- staging addressing (linear LDS dest + pre-swizzled global source) ----
  // dest byte (per lane) = q*8192 + wid*1024 + lane*16  ->  row = q*64+wid*8+(lane>>3), slot = lane&7
  // content must be global slot  s ^ (row&7)  with row&7 = lane>>3:
  const int gslot = ((sw ^ (lane >> 3)) * 8);             // element offset in k
  const int srow  = wid * 8 + (lane >> 3);                // row for q=0
  const unsigned short* Ag = Eb + (size_t)(m_tile * BM + srow) * D_K + gslot;
  const unsigned short* Bg = Wb + (size_t)(n_tile * BN + srow) * D_K + gslot;
  // +q*64 rows = +131072 elements; +k-tile t = +t*64 elements

  // ---- fragment read offsets (swizzled): byte = row*128 + ((slot ^ (row&7))<<4) ----
  int rowA[4], rowB[4];
#pragma unroll
  for (int i = 0; i < 4; ++i) rowA[i] = (wm * 64 + i * 16 + l16) * 128;
#pragma unroll
  for (int j = 0; j < 4; ++j) rowB[j] = (wn * 64 + j * 16 + l16) * 128;
  const int s0 = ((lhi)     ^ sw) << 4;   // kk=0: slot = lhi
  const int s1 = ((4 + lhi) ^ sw) << 4;   // kk=1: slot = 4+lhi

  f32x4 acc[4][4] = {};

  // ---- prologue: stage tile0 -> buf0, tile1 -> buf1; wait oldest 6 ----
  {
    const unsigned short* a = Ag;
    const unsigned short* b = Bg;
    glds16(a,           lds + wid * 1024);
    glds16(a + 131072,  lds + 8192 + wid * 1024);
    glds16(b,           lds + ABYTES + wid * 1024);
    glds16(b + 131072,  lds + ABYTES + 8192  + wid * 1024);
    glds16(b + 262144,  lds + ABYTES + 16384 + wid * 1024);
    glds16(b + 393216,  lds + ABYTES + 24576 + wid * 1024);
    const unsigned short* a1 = Ag + 64;
    const unsigned short* b1 = Bg + 64;
    glds16(a1,          lds + BUFB + wid * 1024);
    glds16(a1 + 131072, lds + BUFB + 8192 + wid * 1024);
    glds16(b1,          lds + BUFB + ABYTES + wid * 1024);
    glds16(b1 + 131072, lds + BUFB + ABYTES + 8192  + wid * 1024);
    glds16(b1 + 262144, lds + BUFB + ABYTES + 16384 + wid * 1024);
    glds16(b1 + 393216, lds + BUFB + ABYTES + 24576 + wid * 1024);
  }
  asm volatile("s_waitcnt vmcnt(6)" ::: "memory");
  bar();

  int c0 = 0, c1 = 1, c2 = 2;
  for (int t = 0; t < NT; ++t) {
    const char* Ac = lds + c0 * BUFB;
    const char* Bc = Ac + ABYTES;
    char*       Sd = lds + c2 * BUFB;               // dest for tile t+2
    const unsigned short* a2 = Ag + (size_t)(t + 2) * 64;
    const unsigned short* g2 = Bg + (size_t)(t + 2) * 64;
    const bool st = (t < NT - 2);

    // ---------- phase 0 (kk = 0) ----------
    bf16x8 af[4], bf[4];
#pragma unroll
    for (int i = 0; i < 4; ++i) af[i] = *(const bf16x8*)(Ac + rowA[i] + s0);
#pragma unroll
    for (int j = 0; j < 4; ++j) bf[j] = *(const bf16x8*)(Bc + rowB[j] + s0);
    if (st) {
      glds16(a2,          Sd + wid * 1024);
      glds16(a2 + 131072, Sd + 8192 + wid * 1024);
      glds16(g2,          Sd + ABYTES + wid * 1024);
    }
    bar();
    __builtin_amdgcn_s_setprio(1);
#pragma unroll
    for (int i = 0; i < 4; ++i)
#pragma unroll
      for (int j = 0; j < 4; ++j)
        acc[i][j] = __builtin_amdgcn_mfma_f32_16x16x32_bf16(af[i], bf[j], acc[i][j], 0, 0, 0);
    __builtin_amdgcn_s_setprio(0);
    bar();

    // ---------- phase 1 (kk = 1) ----------
#pragma unroll
    for (int i = 0; i < 4; ++i) af[i] = *(const bf16x8*)(Ac + rowA[i] + s1);
#pragma unroll
    for (int j = 0; j < 4; ++j) bf[j] = *(const bf16x8*)(Bc + rowB[j] + s1);
    if (st) {
      glds16(g2 + 131072, Sd + ABYTES + 8192  + wid * 1024);
      glds16(g2 + 262144, Sd + ABYTES + 16384 + wid * 1024);
      glds16(g2 + 393216, Sd + ABYTES + 24576 + wid * 1024);
    }
    bar();
    __builtin_amdgcn_s_setprio(1);
#pragma unroll
    for (int i = 0; i < 4; ++i)
#pragma unroll
      for (int j = 0; j < 4; ++j)
        acc[i][j] = __builtin_amdgcn_mfma_f32_16x16x32_bf16(af[i], bf[j], acc[i][j], 0, 0, 0);
    __builtin_amdgcn_s_setprio(0);
    // tile-end: counted wait (never 0 in steady state), then barrier
    if (t < NT - 2)       asm volatile("s_waitcnt vmcnt(6)" ::: "memory");
    else if (t == NT - 2) asm volatile("s_waitcnt vmcnt(0)" ::: "memory");
    bar();

    const int tmp = c0; c0 = c1; c1 = c2; c2 = tmp;
  }

  // ---------- epilogue: per-row (max, sumexp, sum) + label gather ----------
  const int row_base = m_tile * BM;
  const int col_base = n_tile * BN + wn * 64;

#pragma unroll
  for (int i = 0; i < 4; ++i) {
#pragma unroll
    for (int r = 0; r < 4; ++r) {
      const int rt  = wm * 64 + i * 16 + lhi * 4 + r;
      const int row = row_base + rt;
      const int lab = labels[row];
      const int rel = lab - col_base - l16;
#pragma unroll
      for (int j = 0; j < 4; ++j) {
        if (rel == j * 16) ly[row] = acc[i][j][r];   // compile-time acc index
      }

      float mx = -INFINITY, smv = 0.f;
#pragma unroll
      for (int j = 0; j < 4; ++j) {
        const bool v = (col_base + j * 16 + l16) < N_CLS;
        const float x = acc[i][j][r];
        if (v) { mx = fmaxf(mx, x); smv += x; }
      }
#pragma unroll
      for (int d = 1; d < 16; d <<= 1) {
        mx = fmaxf(mx, __shfl_xor(mx, d));
        smv += __shfl_xor(smv, d);
      }
      float se = 0.f;
#pragma unroll
      for (int j = 0; j < 4; ++j) {
        const bool v = (col_base + j * 16 + l16) < N_CLS;
        if (v) se += __expf(acc[i][j][r] - mx);
      }
#pragma unroll
      for (int d = 1; d < 16; d <<= 1) se += __shfl_xor(se, d);

      if (l16 == 0) { s_m[rt][wn] = mx; s_s[rt][wn] = se; s_t[rt][wn] = smv; }
    }
  }
  __syncthreads();
  if (tid < BM) {
    float M = -INFINITY;
#pragma unroll
    for (int g = 0; g < 4; ++g) M = fmaxf(M, s_m[tid][g]);
    float S = 0.f, T = 0.f;
#pragma unroll
    for (int g = 0; g < 4; ++g) {
      S += s_s[tid][g] * __expf(s_m[tid][g] - M);
      T += s_t[tid][g];
    }
    const size_t o = (size_t)n_tile * B_ROWS + row_base + tid;
    pm[o] = M; ps[o] = S; pt[o] = T;
  }
}

// ---------- final combine: GN partials per row -> loss ----------
__global__ void ce_reduce(const float* __restrict__ pm, const float* __restrict__ ps,
                          const float* __restrict__ pt, const float* __restrict__ ly,
                          float* __restrict__ out)
{
  const int tid = threadIdx.x;
  const int row = blockIdx.x * blockDim.x + tid;
  float M = -INFINITY, S = 0.f, T = 0.f;
  for (int nt = 0; nt < GN; ++nt) {
    const size_t o = (size_t)nt * B_ROWS + row;
    const float m = pm[o], s = ps[o], t = pt[o];
    const float Mn = fmaxf(M, m);
    S = S * __expf(M - Mn) + s * __expf(m - Mn);
    M = Mn;
    T += t;
  }
  const float lse = M + logf(S);
  float per = lse - 0.9f * ly[row] - 0.1f * (T * (1.0f / (float)N_CLS));
#pragma unroll
  for (int d = 1; d < 64; d <<= 1) per += __shfl_xor(per, d);
  __shared__ float red[4];
  if ((tid & 63) == 0) red[tid >> 6] = per;
  __syncthreads();
  if (tid == 0)
    atomicAdd(out, (red[0] + red[1] + red[2] + red[3]) * (1.0f / B_ROWS));
}

extern "C" void kernel_launch(void* const* d_in, const int* in_sizes, int n_in,
                              void* d_out, int out_size, void* d_ws, size_t ws_size,
                              hipStream_t stream)
{
  const float* E      = (const float*)d_in[0];
  const int*   labels = (const int*)  d_in[1];
  const float* W      = (const float*)d_in[2];
  float* out = (float*)d_out;

  char* ws = (char*)d_ws;
  unsigned short* Wb = (unsigned short*)ws;
  size_t off = (size_t)N_PAD * D_K * 2;            // 206,569,472 B
  unsigned short* Eb = (unsigned short*)(ws + off);
  off += (size_t)B_ROWS * D_K * 2;                 // + 8,388,608 B
  float* pm = (float*)(ws + off); off += (size_t)GN * B_ROWS * 4;
  float* ps = (float*)(ws + off); off += (size_t)GN * B_ROWS * 4;
  float* pt = (float*)(ws + off); off += (size_t)GN * B_ROWS * 4;
  float* ly = (float*)(ws + off);                  // total ~220 MB

  hipMemsetAsync(d_out, 0, sizeof(float), stream);
  conv_w<<<dim3(2048), dim3(256), 0, stream>>>(W, Wb);
  conv_e<<<dim3(512),  dim3(256), 0, stream>>>(E, Eb);
  gemm_ce<<<dim3(NWG), dim3(512), 0, stream>>>(Eb, Wb, labels, pm, ps, pt, ly);
  ce_reduce<<<dim3(B_ROWS / 256), dim3(256), 0, stream>>>(pm, ps, pt, ly, out);
}

// Round 4
// 669.929 us; speedup vs baseline: 8.1753x; 1.0425x over previous
//
#include <hip/hip_runtime.h>
#include <math.h>

#define B_ROWS 2048
#define D_K    2048
#define N_CLS  50257
#define BM     256
#define BN     256
#define BK     64
#define NT     (D_K / BK)       // 32 K-tiles
#define GM     8                // 2048/256 m-tiles
#define GN     197              // ceil(50257/256) n-tiles
#define N_PAD  (GN * BN)        // 50432
#define NWG    (GM * GN)        // 1576 = 8*197 (bijective XCD swizzle)

// LDS map: buffer b at b*65536. A region [2 kk][256][32] bf16 (32KB),
// B region at +32768 same. Stats at 131072.
#define BUFB   65536
#define HREG   16384            // bytes per kk-half region
#define STATS  131072

typedef __attribute__((ext_vector_type(8))) short          bf16x8;
typedef __attribute__((ext_vector_type(4))) float          f32x4;
typedef __attribute__((ext_vector_type(8))) unsigned short u16x8;

typedef __attribute__((address_space(1))) const void as1cv;
typedef __attribute__((address_space(3))) void       as3v;

__device__ __forceinline__ void glds16(const void* g, void* l) {
  __builtin_amdgcn_global_load_lds((as1cv*)g, (as3v*)l, 16, 0, 0);
}
__device__ __forceinline__ void bar() {
  __builtin_amdgcn_sched_barrier(0);
  __builtin_amdgcn_s_barrier();
  __builtin_amdgcn_sched_barrier(0);
}

__device__ __forceinline__ unsigned short f2bf(float x) {
  unsigned int u = __builtin_bit_cast(unsigned int, x);
  u += 0x7fffu + ((u >> 16) & 1u);   // RNE
  return (unsigned short)(u >> 16);
}

// ---------- fp32 -> bf16 (W zero-padded to N_PAD rows) ----------
__global__ void conv_w(const float* __restrict__ W, unsigned short* __restrict__ Wb) {
  const size_t NU = (size_t)N_PAD * D_K / 8;
  const size_t stride = (size_t)gridDim.x * blockDim.x;
  for (size_t u = (size_t)blockIdx.x * blockDim.x + threadIdx.x; u < NU; u += stride) {
    const size_t e = u * 8;
    u16x8 o = {0, 0, 0, 0, 0, 0, 0, 0};
    if ((e >> 11) < (size_t)N_CLS) {
      const float4 a = *(const float4*)(W + e);
      const float4 b = *(const float4*)(W + e + 4);
      o[0] = f2bf(a.x); o[1] = f2bf(a.y); o[2] = f2bf(a.z); o[3] = f2bf(a.w);
      o[4] = f2bf(b.x); o[5] = f2bf(b.y); o[6] = f2bf(b.z); o[7] = f2bf(b.w);
    }
    *(u16x8*)(Wb + e) = o;
  }
}

__global__ void conv_e(const float* __restrict__ E, unsigned short* __restrict__ Eb) {
  const size_t NU = (size_t)B_ROWS * D_K / 8;
  const size_t stride = (size_t)gridDim.x * blockDim.x;
  for (size_t u = (size_t)blockIdx.x * blockDim.x + threadIdx.x; u < NU; u += stride) {
    const size_t e = u * 8;
    const float4 a = *(const float4*)(E + e);
    const float4 b = *(const float4*)(E + e + 4);
    u16x8 o;
    o[0] = f2bf(a.x); o[1] = f2bf(a.y); o[2] = f2bf(a.z); o[3] = f2bf(a.w);
    o[4] = f2bf(b.x); o[5] = f2bf(b.y); o[6] = f2bf(b.z); o[7] = f2bf(b.w);
    *(u16x8*)(Eb + e) = o;
  }
}

// ---------- fused GEMM + per-tile row stats ----------
// 256x256 tile, BK=64, 8 waves = 2m x 4n, per-wave 128x64 (acc[8][4]).
// kk-major LDS (conflict-free), 2-buffer, per-phase counted vmcnt(4).
__global__ __launch_bounds__(512, 2) void gemm_ce(
    const unsigned short* __restrict__ Eb,
    const unsigned short* __restrict__ Wb,
    const int* __restrict__ labels,
    float* __restrict__ pm, float* __restrict__ ps, float* __restrict__ pt,
    float* __restrict__ ly)
{
  __shared__ __align__(16) char lds[STATS + 12288];
  float (*s_m)[4] = (float (*)[4])(lds + STATS);
  float (*s_s)[4] = (float (*)[4])(lds + STATS + 4096);
  float (*s_t)[4] = (float (*)[4])(lds + STATS + 8192);

  const int tid  = threadIdx.x;
  const int wid  = tid >> 6;
  const int lane = tid & 63;
  const int wm   = wid >> 2;       // 0..1 -> 128-row block
  const int wn   = wid & 3;        // 0..3 -> 64-col block
  const int l16  = lane & 15;
  const int lhi  = lane >> 4;

  // XCD-aware bijective swizzle (NWG = 8*197)
  const int bid     = blockIdx.x;
  const int logical = (bid & 7) * (NWG / 8) + (bid >> 3);
  const int n_tile  = logical / GM;
  const int m_tile  = logical % GM;

  // ---- staging addressing: dest byte (region) = q*8192 + wid*1024 + lane*16
  //      -> row = q*128 + wid*16 + (lane>>2), col = (lane&3)*8 (elements of kk-half)
  const int srow = wid * 16 + (lane >> 2);
  const int scol = (lane & 3) * 8;
  const unsigned short* AgS = Eb + (size_t)(m_tile * BM + srow) * D_K + scol;
  const unsigned short* BgS = Wb + (size_t)(n_tile * BN + srow) * D_K + scol;
  const int ldoff = wid * 1024 + lane * 16;

  // ---- fragment LDS offsets (within a kk-half region) ----
  int offA[8], offB[4];
#pragma unroll
  for (int i = 0; i < 8; ++i) offA[i] = (wm * 128 + i * 16 + l16) * 64 + lhi * 16;
#pragma unroll
  for (int j = 0; j < 4; ++j) offB[j] = (wn * 64 + j * 16 + l16) * 64 + lhi * 16;

  f32x4 acc[8][4] = {};

  // stage kk-half h of tile tt into buffer Sn (4 glds/thread)
#define STAGE(Sn, h, tt)                                                        \
  do {                                                                          \
    const unsigned short* _a = AgS + (size_t)(tt) * 64 + (h) * 32;              \
    const unsigned short* _b = BgS + (size_t)(tt) * 64 + (h) * 32;              \
    char* _d = (Sn) + (h) * HREG + ldoff;                                       \
    glds16(_a,          _d);                                                    \
    glds16(_a + 262144, _d + 8192);                                             \
    glds16(_b,          _d + 32768);                                            \
    glds16(_b + 262144, _d + 32768 + 8192);                                     \
  } while (0)

  // ---- prologue: stage tile 0 (both halves) into buf0 ----
  STAGE(lds, 0, 0);
  STAGE(lds, 1, 0);

  for (int t = 0; t < NT; ++t) {
    const char* Ab = lds + ((t & 1) << 16);
    char*       Sn = lds + (((t & 1) ^ 1) << 16);

#pragma unroll
    for (int h = 0; h < 2; ++h) {
      // entering phase: this phase's staged half must be landed everywhere
      if (t == NT - 1 && h == 1) asm volatile("s_waitcnt vmcnt(0)" ::: "memory");
      else                       asm volatile("s_waitcnt vmcnt(4)" ::: "memory");
      bar();

      bf16x8 af[8], bfr[4];
#pragma unroll
      for (int i = 0; i < 8; ++i) af[i]  = *(const bf16x8*)(Ab + h * HREG + offA[i]);
#pragma unroll
      for (int j = 0; j < 4; ++j) bfr[j] = *(const bf16x8*)(Ab + 32768 + h * HREG + offB[j]);

      if (t < NT - 1) STAGE(Sn, h, t + 1);   // prefetch next tile's half h

      __builtin_amdgcn_s_setprio(1);
#pragma unroll
      for (int i = 0; i < 8; ++i)
#pragma unroll
        for (int j = 0; j < 4; ++j)
          acc[i][j] = __builtin_amdgcn_mfma_f32_16x16x32_bf16(af[i], bfr[j], acc[i][j], 0, 0, 0);
      __builtin_amdgcn_s_setprio(0);
    }
  }
#undef STAGE

  // ---------- epilogue: per-row (max, sumexp, sum) + label gather ----------
  const int row_base = m_tile * BM;
  const int col_base = n_tile * BN + wn * 64;

#pragma unroll
  for (int i = 0; i < 8; ++i) {
#pragma unroll
    for (int r = 0; r < 4; ++r) {
      const int rt  = wm * 128 + i * 16 + lhi * 4 + r;
      const int row = row_base + rt;
      const int lab = labels[row];
      const int rel = lab - col_base - l16;
#pragma unroll
      for (int j = 0; j < 4; ++j) {
        if (rel == j * 16) ly[row] = acc[i][j][r];   // compile-time acc index
      }

      float mx = -INFINITY, smv = 0.f;
#pragma unroll
      for (int j = 0; j < 4; ++j) {
        const bool v = (col_base + j * 16 + l16) < N_CLS;
        const float x = acc[i][j][r];
        if (v) { mx = fmaxf(mx, x); smv += x; }
      }
#pragma unroll
      for (int d = 1; d < 16; d <<= 1) {
        mx = fmaxf(mx, __shfl_xor(mx, d));
        smv += __shfl_xor(smv, d);
      }
      float se = 0.f;
#pragma unroll
      for (int j = 0; j < 4; ++j) {
        const bool v = (col_base + j * 16 + l16) < N_CLS;
        if (v) se += __expf(acc[i][j][r] - mx);
      }
#pragma unroll
      for (int d = 1; d < 16; d <<= 1) se += __shfl_xor(se, d);

      if (l16 == 0) { s_m[rt][wn] = mx; s_s[rt][wn] = se; s_t[rt][wn] = smv; }
    }
  }
  __syncthreads();
  if (tid < BM) {
    float M = -INFINITY;
#pragma unroll
    for (int g = 0; g < 4; ++g) M = fmaxf(M, s_m[tid][g]);
    float S = 0.f, T = 0.f;
#pragma unroll
    for (int g = 0; g < 4; ++g) {
      S += s_s[tid][g] * __expf(s_m[tid][g] - M);
      T += s_t[tid][g];
    }
    const size_t o = (size_t)n_tile * B_ROWS + row_base + tid;
    pm[o] = M; ps[o] = S; pt[o] = T;
  }
}

// ---------- final combine: GN partials per row -> loss ----------
__global__ void ce_reduce(const float* __restrict__ pm, const float* __restrict__ ps,
                          const float* __restrict__ pt, const float* __restrict__ ly,
                          float* __restrict__ out)
{
  const int tid = threadIdx.x;
  const int row = blockIdx.x * blockDim.x + tid;
  float M = -INFINITY, S = 0.f, T = 0.f;
  for (int nt = 0; nt < GN; ++nt) {
    const size_t o = (size_t)nt * B_ROWS + row;
    const float m = pm[o], s = ps[o], t = pt[o];
    const float Mn = fmaxf(M, m);
    S = S * __expf(M - Mn) + s * __expf(m - Mn);
    M = Mn;
    T += t;
  }
  const float lse = M + logf(S);
  float per = lse - 0.9f * ly[row] - 0.1f * (T * (1.0f / (float)N_CLS));
#pragma unroll
  for (int d = 1; d < 64; d <<= 1) per += __shfl_xor(per, d);
  __shared__ float red[4];
  if ((tid & 63) == 0) red[tid >> 6] = per;
  __syncthreads();
  if (tid == 0)
    atomicAdd(out, (red[0] + red[1] + red[2] + red[3]) * (1.0f / B_ROWS));
}

extern "C" void kernel_launch(void* const* d_in, const int* in_sizes, int n_in,
                              void* d_out, int out_size, void* d_ws, size_t ws_size,
                              hipStream_t stream)
{
  const float* E      = (const float*)d_in[0];
  const int*   labels = (const int*)  d_in[1];
  const float* W      = (const float*)d_in[2];
  float* out = (float*)d_out;

  char* ws = (char*)d_ws;
  unsigned short* Wb = (unsigned short*)ws;
  size_t off = (size_t)N_PAD * D_K * 2;            // 206,569,472 B
  unsigned short* Eb = (unsigned short*)(ws + off);
  off += (size_t)B_ROWS * D_K * 2;                 // + 8,388,608 B
  float* pm = (float*)(ws + off); off += (size_t)GN * B_ROWS * 4;
  float* ps = (float*)(ws + off); off += (size_t)GN * B_ROWS * 4;
  float* pt = (float*)(ws + off); off += (size_t)GN * B_ROWS * 4;
  float* ly = (float*)(ws + off);                  // total ~220 MB

  hipMemsetAsync(d_out, 0, sizeof(float), stream);
  conv_w<<<dim3(2048), dim3(256), 0, stream>>>(W, Wb);
  conv_e<<<dim3(512),  dim3(256), 0, stream>>>(E, Eb);
  gemm_ce<<<dim3(NWG), dim3(512), 0, stream>>>(Eb, Wb, labels, pm, ps, pt, ly);
  ce_reduce<<<dim3(B_ROWS / 256), dim3(256), 0, stream>>>(pm, ps, pt, ly, out);
}

// Round 5
// 659.206 us; speedup vs baseline: 8.3082x; 1.0163x over previous
//
#include <hip/hip_runtime.h>
#include <math.h>

#define B_ROWS 2048
#define D_K    2048
#define N_CLS  50257
#define BM     256
#define BN     256
#define BK     64
#define NT     (D_K / BK)       // 32 K-tiles
#define GM     8                // 2048/256 m-tiles
#define GN     197              // ceil(50257/256) n-tiles
#define N_PAD  (GN * BN)        // 50432
#define NWG    (GM * GN)        // 1576 = 8*197 (bijective XCD swizzle)

// LDS: buffer b at b*65536. A: [2 half][256 rows][32 cols] bf16 (32KB),
// B at +32768 same. Swizzle: 16B slot position p = content_slot ^ ((row>>1)&3).
#define BUFB   65536
#define HREG   16384            // bytes per kk-half region
#define STATS  131072

typedef __attribute__((ext_vector_type(8))) short          bf16x8;
typedef __attribute__((ext_vector_type(4))) float          f32x4;
typedef __attribute__((ext_vector_type(8))) unsigned short u16x8;

typedef __attribute__((address_space(1))) const void as1cv;
typedef __attribute__((address_space(3))) void       as3v;

__device__ __forceinline__ void glds16(const void* g, void* l) {
  __builtin_amdgcn_global_load_lds((as1cv*)g, (as3v*)l, 16, 0, 0);
}
__device__ __forceinline__ void bar() {
  __builtin_amdgcn_sched_barrier(0);
  __builtin_amdgcn_s_barrier();
  __builtin_amdgcn_sched_barrier(0);
}
__device__ __forceinline__ void lgkm0() {
  asm volatile("s_waitcnt lgkmcnt(0)" ::: "memory");
  __builtin_amdgcn_sched_barrier(0);
}

__device__ __forceinline__ unsigned short f2bf(float x) {
  unsigned int u = __builtin_bit_cast(unsigned int, x);
  u += 0x7fffu + ((u >> 16) & 1u);   // RNE
  return (unsigned short)(u >> 16);
}

// ---------- fp32 -> bf16 (W zero-padded to N_PAD rows) ----------
__global__ void conv_w(const float* __restrict__ W, unsigned short* __restrict__ Wb) {
  const size_t NU = (size_t)N_PAD * D_K / 8;
  const size_t stride = (size_t)gridDim.x * blockDim.x;
  for (size_t u = (size_t)blockIdx.x * blockDim.x + threadIdx.x; u < NU; u += stride) {
    const size_t e = u * 8;
    u16x8 o = {0, 0, 0, 0, 0, 0, 0, 0};
    if ((e >> 11) < (size_t)N_CLS) {
      const float4 a = *(const float4*)(W + e);
      const float4 b = *(const float4*)(W + e + 4);
      o[0] = f2bf(a.x); o[1] = f2bf(a.y); o[2] = f2bf(a.z); o[3] = f2bf(a.w);
      o[4] = f2bf(b.x); o[5] = f2bf(b.y); o[6] = f2bf(b.z); o[7] = f2bf(b.w);
    }
    *(u16x8*)(Wb + e) = o;
  }
}

__global__ void conv_e(const float* __restrict__ E, unsigned short* __restrict__ Eb) {
  const size_t NU = (size_t)B_ROWS * D_K / 8;
  const size_t stride = (size_t)gridDim.x * blockDim.x;
  for (size_t u = (size_t)blockIdx.x * blockDim.x + threadIdx.x; u < NU; u += stride) {
    const size_t e = u * 8;
    const float4 a = *(const float4*)(E + e);
    const float4 b = *(const float4*)(E + e + 4);
    u16x8 o;
    o[0] = f2bf(a.x); o[1] = f2bf(a.y); o[2] = f2bf(a.z); o[3] = f2bf(a.w);
    o[4] = f2bf(b.x); o[5] = f2bf(b.y); o[6] = f2bf(b.z); o[7] = f2bf(b.w);
    *(u16x8*)(Eb + e) = o;
  }
}

// ---------- fused GEMM + per-tile row stats ----------
// 256x256, BK=64, 8 waves (2m x 4n), per-wave 128x64, acc[8][4].
// 4 phases/K-tile (kk-half x m-half), counted vmcnt(4), swizzled kk-major LDS.
__global__ __launch_bounds__(512, 2) void gemm_ce(
    const unsigned short* __restrict__ Eb,
    const unsigned short* __restrict__ Wb,
    const int* __restrict__ labels,
    float* __restrict__ pm, float* __restrict__ ps, float* __restrict__ pt,
    float* __restrict__ ly)
{
  __shared__ __align__(16) char lds[STATS + 12288];
  float (*s_m)[4] = (float (*)[4])(lds + STATS);
  float (*s_s)[4] = (float (*)[4])(lds + STATS + 4096);
  float (*s_t)[4] = (float (*)[4])(lds + STATS + 8192);

  const int tid  = threadIdx.x;
  const int wid  = tid >> 6;
  const int lane = tid & 63;
  const int wm   = wid >> 2;       // 0..1 -> 128-row block
  const int wn   = wid & 3;        // 0..3 -> 64-col block
  const int l16  = lane & 15;
  const int lhi  = lane >> 4;

  // XCD-aware bijective swizzle (NWG = 8*197)
  const int bid     = blockIdx.x;
  const int logical = (bid & 7) * (NWG / 8) + (bid >> 3);
  const int n_tile  = logical / GM;
  const int m_tile  = logical % GM;

  // ---- staging: dest (region-linear) = q*8192 + wid*1024 + lane*16
  //      -> row = q*128 + wid*16 + (lane>>2), slot position = lane&3
  //      content slot = (lane&3) ^ swz(row), swz(row) = (row>>1)&3 = (lane>>3)&3
  const int gk   = (((lane & 3) ^ ((lane >> 3) & 3)) * 8);
  const int srow = wid * 16 + (lane >> 2);
  const unsigned short* AgS = Eb + (size_t)(m_tile * BM + srow) * D_K + gk;
  const unsigned short* BgS = Wb + (size_t)(n_tile * BN + srow) * D_K + gk;
  const int ldoff = wid * 1024 + lane * 16;
  // +q -> +262144 elements (128 rows); +h -> +32 elements; +tile -> +64 elements

  // ---- fragment LDS offsets (within a kk-half region) ----
  const int sws = (lhi ^ ((l16 >> 1) & 3)) << 4;
  int offA[8], offB[4];
#pragma unroll
  for (int i = 0; i < 8; ++i) offA[i] = (wm * 128 + i * 16 + l16) * 64 + sws;
#pragma unroll
  for (int j = 0; j < 4; ++j) offB[j] = 32768 + (wn * 64 + j * 16 + l16) * 64 + sws;

  f32x4 acc[8][4] = {};

  // ---- prologue: stage tile 0 into buf0, order Ah0,Bh0,Ah1,Bh1 ----
  {
    char* S = lds;
    glds16(AgS,               S + ldoff);
    glds16(AgS + 262144,      S + 8192 + ldoff);
    glds16(BgS,               S + 32768 + ldoff);
    glds16(BgS + 262144,      S + 32768 + 8192 + ldoff);
    glds16(AgS + 32,          S + HREG + ldoff);
    glds16(AgS + 262144 + 32, S + HREG + 8192 + ldoff);
    glds16(BgS + 32,          S + 32768 + HREG + ldoff);
    glds16(BgS + 262144 + 32, S + 32768 + HREG + 8192 + ldoff);
  }

  for (int t = 0; t < NT; ++t) {
    const char* Rb = lds + ((t & 1) << 16);
    char*       Sb = lds + (((t & 1) ^ 1) << 16);
    const bool  st = (t < NT - 1);
    const unsigned short* An = AgS + (size_t)(t + 1) * 64;
    const unsigned short* Bn = BgS + (size_t)(t + 1) * 64;

    bf16x8 a0, a1, a2, a3, b0, b1, b2, b3;

#define MFMA_ROW(ib, jj, av) acc[ib][jj] = __builtin_amdgcn_mfma_f32_16x16x32_bf16(av, (jj == 0 ? b0 : jj == 1 ? b1 : jj == 2 ? b2 : b3), acc[ib][jj], 0, 0, 0)
#define MFMA16(base)                                                     \
  do {                                                                   \
    _Pragma("unroll")                                                    \
    for (int j = 0; j < 4; ++j) { MFMA_ROW(base + 0, j, a0); }           \
    _Pragma("unroll")                                                    \
    for (int j = 0; j < 4; ++j) { MFMA_ROW(base + 1, j, a1); }           \
    _Pragma("unroll")                                                    \
    for (int j = 0; j < 4; ++j) { MFMA_ROW(base + 2, j, a2); }           \
    _Pragma("unroll")                                                    \
    for (int j = 0; j < 4; ++j) { MFMA_ROW(base + 3, j, a3); }           \
  } while (0)

    // ===== phase 0: h=0, mh=0 =====
    asm volatile("s_waitcnt vmcnt(4)" ::: "memory");
    bar();
    b0 = *(const bf16x8*)(Rb + offB[0]); b1 = *(const bf16x8*)(Rb + offB[1]);
    b2 = *(const bf16x8*)(Rb + offB[2]); b3 = *(const bf16x8*)(Rb + offB[3]);
    a0 = *(const bf16x8*)(Rb + offA[0]); a1 = *(const bf16x8*)(Rb + offA[1]);
    a2 = *(const bf16x8*)(Rb + offA[2]); a3 = *(const bf16x8*)(Rb + offA[3]);
    if (st) { glds16(An, Sb + ldoff); glds16(An + 262144, Sb + 8192 + ldoff); }
    lgkm0();
    __builtin_amdgcn_s_setprio(1);
    MFMA16(0);
    __builtin_amdgcn_s_setprio(0);

    // ===== phase 1: h=0, mh=1 =====
    bar();
    a0 = *(const bf16x8*)(Rb + offA[4]); a1 = *(const bf16x8*)(Rb + offA[5]);
    a2 = *(const bf16x8*)(Rb + offA[6]); a3 = *(const bf16x8*)(Rb + offA[7]);
    if (st) { glds16(Bn, Sb + 32768 + ldoff); glds16(Bn + 262144, Sb + 32768 + 8192 + ldoff); }
    lgkm0();
    __builtin_amdgcn_s_setprio(1);
    MFMA16(4);
    __builtin_amdgcn_s_setprio(0);

    // ===== phase 2: h=1, mh=0 =====
    if (t == NT - 1) asm volatile("s_waitcnt vmcnt(0)" ::: "memory");
    else             asm volatile("s_waitcnt vmcnt(4)" ::: "memory");
    bar();
    b0 = *(const bf16x8*)(Rb + HREG + offB[0]); b1 = *(const bf16x8*)(Rb + HREG + offB[1]);
    b2 = *(const bf16x8*)(Rb + HREG + offB[2]); b3 = *(const bf16x8*)(Rb + HREG + offB[3]);
    a0 = *(const bf16x8*)(Rb + HREG + offA[0]); a1 = *(const bf16x8*)(Rb + HREG + offA[1]);
    a2 = *(const bf16x8*)(Rb + HREG + offA[2]); a3 = *(const bf16x8*)(Rb + HREG + offA[3]);
    if (st) { glds16(An + 32, Sb + HREG + ldoff); glds16(An + 262144 + 32, Sb + HREG + 8192 + ldoff); }
    lgkm0();
    __builtin_amdgcn_s_setprio(1);
    MFMA16(0);
    __builtin_amdgcn_s_setprio(0);

    // ===== phase 3: h=1, mh=1 =====
    bar();
    a0 = *(const bf16x8*)(Rb + HREG + offA[4]); a1 = *(const bf16x8*)(Rb + HREG + offA[5]);
    a2 = *(const bf16x8*)(Rb + HREG + offA[6]); a3 = *(const bf16x8*)(Rb + HREG + offA[7]);
    if (st) { glds16(Bn + 32, Sb + 32768 + HREG + ldoff); glds16(Bn + 262144 + 32, Sb + 32768 + HREG + 8192 + ldoff); }
    lgkm0();
    __builtin_amdgcn_s_setprio(1);
    MFMA16(4);
    __builtin_amdgcn_s_setprio(0);
#undef MFMA16
#undef MFMA_ROW
  }

  // ---------- epilogue: per-row (max, sumexp, sum) + label gather ----------
  const int row_base = m_tile * BM;
  const int col_base = n_tile * BN + wn * 64;

#pragma unroll
  for (int i = 0; i < 8; ++i) {
#pragma unroll
    for (int r = 0; r < 4; ++r) {
      const int rt  = wm * 128 + i * 16 + lhi * 4 + r;
      const int row = row_base + rt;
      const int lab = labels[row];
      const int rel = lab - col_base - l16;
#pragma unroll
      for (int j = 0; j < 4; ++j) {
        if (rel == j * 16) ly[row] = acc[i][j][r];   // compile-time acc index
      }

      float mx = -INFINITY, smv = 0.f;
#pragma unroll
      for (int j = 0; j < 4; ++j) {
        const bool v = (col_base + j * 16 + l16) < N_CLS;
        const float x = acc[i][j][r];
        if (v) { mx = fmaxf(mx, x); smv += x; }
      }
#pragma unroll
      for (int d = 1; d < 16; d <<= 1) {
        mx = fmaxf(mx, __shfl_xor(mx, d));
        smv += __shfl_xor(smv, d);
      }
      float se = 0.f;
#pragma unroll
      for (int j = 0; j < 4; ++j) {
        const bool v = (col_base + j * 16 + l16) < N_CLS;
        if (v) se += __expf(acc[i][j][r] - mx);
      }
#pragma unroll
      for (int d = 1; d < 16; d <<= 1) se += __shfl_xor(se, d);

      if (l16 == 0) { s_m[rt][wn] = mx; s_s[rt][wn] = se; s_t[rt][wn] = smv; }
    }
  }
  __syncthreads();
  if (tid < BM) {
    float M = -INFINITY;
#pragma unroll
    for (int g = 0; g < 4; ++g) M = fmaxf(M, s_m[tid][g]);
    float S = 0.f, T = 0.f;
#pragma unroll
    for (int g = 0; g < 4; ++g) {
      S += s_s[tid][g] * __expf(s_m[tid][g] - M);
      T += s_t[tid][g];
    }
    const size_t o = (size_t)n_tile * B_ROWS + row_base + tid;
    pm[o] = M; ps[o] = S; pt[o] = T;
  }
}

// ---------- final combine: GN partials per row -> loss ----------
__global__ void ce_reduce(const float* __restrict__ pm, const float* __restrict__ ps,
                          const float* __restrict__ pt, const float* __restrict__ ly,
                          float* __restrict__ out)
{
  const int tid = threadIdx.x;
  const int row = blockIdx.x * blockDim.x + tid;
  float M = -INFINITY, S = 0.f, T = 0.f;
  for (int nt = 0; nt < GN; ++nt) {
    const size_t o = (size_t)nt * B_ROWS + row;
    const float m = pm[o], s = ps[o], t = pt[o];
    const float Mn = fmaxf(M, m);
    S = S * __expf(M - Mn) + s * __expf(m - Mn);
    M = Mn;
    T += t;
  }
  const float lse = M + logf(S);
  float per = lse - 0.9f * ly[row] - 0.1f * (T * (1.0f / (float)N_CLS));
#pragma unroll
  for (int d = 1; d < 64; d <<= 1) per += __shfl_xor(per, d);
  __shared__ float red[4];
  if ((tid & 63) == 0) red[tid >> 6] = per;
  __syncthreads();
  if (tid == 0)
    atomicAdd(out, (red[0] + red[1] + red[2] + red[3]) * (1.0f / B_ROWS));
}

extern "C" void kernel_launch(void* const* d_in, const int* in_sizes, int n_in,
                              void* d_out, int out_size, void* d_ws, size_t ws_size,
                              hipStream_t stream)
{
  const float* E      = (const float*)d_in[0];
  const int*   labels = (const int*)  d_in[1];
  const float* W      = (const float*)d_in[2];
  float* out = (float*)d_out;

  char* ws = (char*)d_ws;
  unsigned short* Wb = (unsigned short*)ws;
  size_t off = (size_t)N_PAD * D_K * 2;            // 206,569,472 B
  unsigned short* Eb = (unsigned short*)(ws + off);
  off += (size_t)B_ROWS * D_K * 2;                 // + 8,388,608 B
  float* pm = (float*)(ws + off); off += (size_t)GN * B_ROWS * 4;
  float* ps = (float*)(ws + off); off += (size_t)GN * B_ROWS * 4;
  float* pt = (float*)(ws + off); off += (size_t)GN * B_ROWS * 4;
  float* ly = (float*)(ws + off);                  // total ~220 MB

  hipMemsetAsync(d_out, 0, sizeof(float), stream);
  conv_w<<<dim3(2048), dim3(256), 0, stream>>>(W, Wb);
  conv_e<<<dim3(512),  dim3(256), 0, stream>>>(E, Eb);
  gemm_ce<<<dim3(NWG), dim3(512), 0, stream>>>(Eb, Wb, labels, pm, ps, pt, ly);
  ce_reduce<<<dim3(B_ROWS / 256), dim3(256), 0, stream>>>(pm, ps, pt, ly, out);
}